// Round 5
// baseline (364.829 us; speedup 1.0000x reference)
//
#include <hip/hip_runtime.h>
#include <hip/hip_bf16.h>

#define HIDSZ 256
#define NAGENTS 8
#define NMODELS 64
#define NACTIONS 16
#define BN 256
#define IN_DIM 512
#define COMMSZ (HIDSZ * NAGENTS)   // 2048

// output flat offsets (f32 elements), return order: action, baseline, hid, comm
#define OUT_ACT 0
#define OUT_BASE (BN * NACTIONS)                    // 4096
#define OUT_HID (OUT_BASE + BN)                     // 4352
#define OUT_COMM (OUT_HID + BN * HIDSZ)             // 69888

// ---------------- K0: counting sort of rows by model id ----------------
__global__ void k_sort(const int* __restrict__ ids,
                       int* __restrict__ model_start,
                       int* __restrict__ row_of) {
    __shared__ int cnt[NMODELS];
    __shared__ int base[NMODELS + 1];
    int t = threadIdx.x;
    if (t < NMODELS) cnt[t] = 0;
    __syncthreads();
    int id = ids[t];
    atomicAdd(&cnt[id], 1);
    __syncthreads();
    if (t == 0) {
        int s = 0;
        for (int m = 0; m < NMODELS; ++m) { base[m] = s; s += cnt[m]; }
        base[NMODELS] = s;
    }
    __syncthreads();
    if (t <= NMODELS) model_start[t] = base[t];
    __syncthreads();
    int pos = atomicAdd(&base[id], 1);
    row_of[pos] = t;
}

// ---------------- K1: hid = relu(enc(inp) + rnn(prev_hid) + comm + biases) ----
__global__ __launch_bounds__(256) void k_hid(
    const float* __restrict__ inp, const float* __restrict__ prev_hid,
    const float* __restrict__ comm_in,
    const float* __restrict__ enc_w, const float* __restrict__ enc_b,
    const float* __restrict__ rnn_w, const float* __restrict__ rnn_b,
    const int* __restrict__ model_start, const int* __restrict__ row_of,
    float* __restrict__ out)
{
    int m = blockIdx.x;
    int chunk = blockIdx.y;            // 4 chunks of 64 cols
    int s = model_start[m], e = model_start[m + 1];
    int R = e - s;
    if (R == 0) return;
    __shared__ float xs[4][IN_DIM + HIDSZ];   // 4 rows x 768 f32
    int t = threadIdx.x;
    int lane = t & 63;
    int slot = t >> 6;                 // wave index = row slot
    int col = chunk * 64 + lane;

    for (int g = blockIdx.z; g * 4 < R; g += gridDim.z) {
        __syncthreads();
        for (int rr = 0; rr < 4; ++rr) {
            int ri = g * 4 + rr;
            int b = (ri < R) ? row_of[s + ri] : -1;
            for (int j = t; j < IN_DIM + HIDSZ; j += 256) {
                float v = 0.f;
                if (b >= 0)
                    v = (j < IN_DIM) ? inp[b * IN_DIM + j]
                                     : prev_hid[b * HIDSZ + (j - IN_DIM)];
                xs[rr][j] = v;
            }
        }
        __syncthreads();
        int ri = g * 4 + slot;
        if (ri < R) {
            int b = row_of[s + ri];
            float acc = 0.f;
            #pragma unroll 4
            for (int i = 0; i < IN_DIM; ++i)
                acc += xs[slot][i] * enc_w[i * HIDSZ + col];
            const float* rw = rnn_w + (size_t)m * HIDSZ * HIDSZ;
            #pragma unroll 4
            for (int i = 0; i < HIDSZ; ++i)
                acc += xs[slot][IN_DIM + i] * rw[i * HIDSZ + col];
            float cs = 0.f;
            #pragma unroll
            for (int a = 0; a < NAGENTS; ++a)
                cs += comm_in[(b * NAGENTS + a) * HIDSZ + col];
            acc += cs + enc_b[col] + rnn_b[m * HIDSZ + col];
            out[OUT_HID + b * HIDSZ + col] = fmaxf(acc, 0.f);
        }
    }
}

// ---------------- K2: comm_out (y<2) + act softmax / baseline (y==2) ----------
__global__ __launch_bounds__(256) void k_out(
    const float* __restrict__ act_w, const float* __restrict__ act_b,
    const float* __restrict__ base_w, const float* __restrict__ base_b,
    const float* __restrict__ comm_w, const float* __restrict__ comm_b,
    const int* __restrict__ model_start, const int* __restrict__ row_of,
    float* __restrict__ out)
{
    int m = blockIdx.x;
    int y = blockIdx.y;
    int s = model_start[m], e = model_start[m + 1];
    int R = e - s;
    if (R == 0) return;
    int t = threadIdx.x;
    const float* hid = out + OUT_HID;

    if (y == 2) {
        if (blockIdx.z != 0) return;
        // ---- action probs: 16 row-slots x 16 actions ----
        int o = t & 15, rs = t >> 4;
        const float* aw = act_w + m * HIDSZ * NACTIONS;
        for (int r0 = 0; r0 < R; r0 += 16) {
            int ri = r0 + rs;
            if (ri < R) {
                int b = row_of[s + ri];
                float acc = act_b[m * NACTIONS + o];
                #pragma unroll 4
                for (int i = 0; i < HIDSZ; ++i)
                    acc += hid[b * HIDSZ + i] * aw[i * NACTIONS + o];
                float mx = acc;
                #pragma unroll
                for (int d = 1; d < 16; d <<= 1) mx = fmaxf(mx, __shfl_xor(mx, d, 64));
                float ex = __expf(acc - mx);
                float sm = ex;
                #pragma unroll
                for (int d = 1; d < 16; d <<= 1) sm += __shfl_xor(sm, d, 64);
                out[OUT_ACT + b * NACTIONS + o] = ex / sm;
            }
        }
        // ---- baseline: one wave per row ----
        int lane = t & 63, wv = t >> 6;
        const float* bw = base_w + m * HIDSZ;
        for (int ri = wv; ri < R; ri += 4) {
            int b = row_of[s + ri];
            float p = 0.f;
            #pragma unroll
            for (int i = lane; i < HIDSZ; i += 64)
                p += hid[b * HIDSZ + i] * bw[i];
            #pragma unroll
            for (int d = 1; d < 64; d <<= 1) p += __shfl_xor(p, d, 64);
            if (lane == 0) out[OUT_BASE + b] = p + base_b[m];
        }
        return;
    }

    // ---- comm_out: 1024-col half y, 4 cols/thread (16B float4 loads) --------
    __shared__ float hs[8][HIDSZ];
    int c0 = y * 1024 + t * 4;
    const float* cw = comm_w + (size_t)m * HIDSZ * COMMSZ;
    float cb0 = comm_b[m * COMMSZ + c0 + 0];
    float cb1 = comm_b[m * COMMSZ + c0 + 1];
    float cb2 = comm_b[m * COMMSZ + c0 + 2];
    float cb3 = comm_b[m * COMMSZ + c0 + 3];

    for (int g = blockIdx.z; g * 8 < R; g += gridDim.z) {
        __syncthreads();
        for (int rr = 0; rr < 8; ++rr) {
            int ri = g * 8 + rr;
            float v = 0.f;
            if (ri < R) {
                int b = row_of[s + ri];
                v = hid[b * HIDSZ + t];
            }
            hs[rr][t] = v;
        }
        __syncthreads();
        float acc[8][4];
        #pragma unroll
        for (int r = 0; r < 8; ++r)
            #pragma unroll
            for (int c = 0; c < 4; ++c) acc[r][c] = 0.f;

        // 8-deep unroll: ~8x1KB coalesced loads in flight per wave to cover
        // the ~2.4MB HBM bandwidth-delay product.
        #pragma unroll 8
        for (int i = 0; i < HIDSZ; ++i) {
            float4 w = *reinterpret_cast<const float4*>(cw + (size_t)i * COMMSZ + c0);
            #pragma unroll
            for (int r = 0; r < 8; ++r) {
                float h = hs[r][i];
                acc[r][0] += h * w.x;
                acc[r][1] += h * w.y;
                acc[r][2] += h * w.z;
                acc[r][3] += h * w.w;
            }
        }
        #pragma unroll
        for (int r = 0; r < 8; ++r) {
            int ri = g * 8 + r;
            if (ri < R) {
                int b = row_of[s + ri];
                float4 o;
                o.x = acc[r][0] + cb0;
                o.y = acc[r][1] + cb1;
                o.z = acc[r][2] + cb2;
                o.w = acc[r][3] + cb3;
                *reinterpret_cast<float4*>(&out[OUT_COMM + b * COMMSZ + c0]) = o;
            }
        }
    }
}

extern "C" void kernel_launch(void* const* d_in, const int* in_sizes, int n_in,
                              void* d_out, int out_size, void* d_ws, size_t ws_size,
                              hipStream_t stream) {
    const float* inp      = (const float*)d_in[0];
    const float* prev_hid = (const float*)d_in[1];
    const float* comm_in  = (const float*)d_in[2];
    const int*   ids      = (const int*)d_in[3];
    const float* enc_w    = (const float*)d_in[4];
    const float* enc_b    = (const float*)d_in[5];
    const float* rnn_w    = (const float*)d_in[6];
    const float* rnn_b    = (const float*)d_in[7];
    const float* act_w    = (const float*)d_in[8];
    const float* act_b    = (const float*)d_in[9];
    const float* base_w   = (const float*)d_in[10];
    const float* base_b   = (const float*)d_in[11];
    const float* comm_w   = (const float*)d_in[12];
    const float* comm_b   = (const float*)d_in[13];
    float* out = (float*)d_out;

    int* model_start = (int*)d_ws;            // 65 ints
    int* row_of      = model_start + 72;      // 256 ints

    hipLaunchKernelGGL(k_sort, dim3(1), dim3(256), 0, stream,
                       ids, model_start, row_of);
    hipLaunchKernelGGL(k_hid, dim3(64, 4, 4), dim3(256), 0, stream,
                       inp, prev_hid, comm_in, enc_w, enc_b, rnn_w, rnn_b,
                       model_start, row_of, out);
    hipLaunchKernelGGL(k_out, dim3(64, 3, 2), dim3(256), 0, stream,
                       act_w, act_b, base_w, base_b, comm_w, comm_b,
                       model_start, row_of, out);
}

// Round 6
// 280.163 us; speedup vs baseline: 1.3022x; 1.3022x over previous
//
#include <hip/hip_runtime.h>

#define HIDSZ 256
#define NAGENTS 8
#define NMODELS 64
#define NACTIONS 16
#define BN 256
#define IN_DIM 512
#define COMMSZ 2048

// output flat offsets (f32 elements), return order: action, baseline, hid, comm
#define OUT_ACT 0
#define OUT_BASE (BN * NACTIONS)                    // 4096
#define OUT_HID (OUT_BASE + BN)                     // 4352
#define OUT_COMM (OUT_HID + BN * HIDSZ)             // 69888

// ---------------- K0: counting sort of rows by model id ----------------
__global__ void k_sort(const int* __restrict__ ids,
                       int* __restrict__ model_start,
                       int* __restrict__ row_of) {
    __shared__ int cnt[NMODELS];
    __shared__ int base[NMODELS + 1];
    int t = threadIdx.x;
    if (t < NMODELS) cnt[t] = 0;
    __syncthreads();
    int id = ids[t];
    atomicAdd(&cnt[id], 1);
    __syncthreads();
    if (t == 0) {
        int s = 0;
        for (int m = 0; m < NMODELS; ++m) { base[m] = s; s += cnt[m]; }
        base[NMODELS] = s;
    }
    __syncthreads();
    if (t <= NMODELS) model_start[t] = base[t];
    __syncthreads();
    int pos = atomicAdd(&base[id], 1);
    row_of[pos] = t;
}

// ---------------- K1: hid = relu(enc(inp) + rnn(prev_hid) + comm + biases) ----
// Per block: model m, 4-row group. 4 waves split the reduction dim
// (enc: 128 i each, rnn: 64 i each), float4 weight loads with an explicit
// 16-deep register pipeline; cross-wave reduction through LDS.
__global__ __launch_bounds__(256) void k_hid(
    const float* __restrict__ inp, const float* __restrict__ prev_hid,
    const float* __restrict__ comm_in,
    const float* __restrict__ enc_w, const float* __restrict__ enc_b,
    const float* __restrict__ rnn_w, const float* __restrict__ rnn_b,
    const int* __restrict__ model_start, const int* __restrict__ row_of,
    float* __restrict__ out)
{
    int m = blockIdx.x;
    int s = model_start[m];
    int R = model_start[m + 1] - s;
    if (R == 0) return;
    int t = threadIdx.x, lane = t & 63, w = t >> 6;

    __shared__ float4 xs4[4][192];           // [row][float4] inp(128)+prev(64), 12 KB
    __shared__ float red[4][4][HIDSZ];       // [wave][row][col] partials, 16 KB

    for (int g = blockIdx.y; g * 4 < R; g += gridDim.y) {
        __syncthreads();
        {   // wave w stages row w of this group
            int ri = g * 4 + w;
            float4 z4 = make_float4(0.f, 0.f, 0.f, 0.f);
            if (ri < R) {
                int b = row_of[s + ri];
                const float4* ip = (const float4*)(inp + (size_t)b * IN_DIM);
                const float4* ph = (const float4*)(prev_hid + (size_t)b * HIDSZ);
                xs4[w][lane]       = ip[lane];
                xs4[w][64 + lane]  = ip[64 + lane];
                xs4[w][128 + lane] = ph[lane];
            } else {
                xs4[w][lane] = z4; xs4[w][64 + lane] = z4; xs4[w][128 + lane] = z4;
            }
        }
        __syncthreads();

        float acc[4][4];
        #pragma unroll
        for (int r = 0; r < 4; ++r)
            acc[r][0] = acc[r][1] = acc[r][2] = acc[r][3] = 0.f;

        const float* xs = (const float*)xs4;          // [4][768]
        const float4* ew4 = (const float4*)enc_w;     // [512][64]

        // enc partial: i in [128w, 128w+128), 16-deep explicit pipeline
        for (int i0 = 0; i0 < 128; i0 += 16) {
            float4 wv[16];
            #pragma unroll
            for (int u = 0; u < 16; ++u)
                wv[u] = ew4[(size_t)(128 * w + i0 + u) * 64 + lane];
            #pragma unroll
            for (int u = 0; u < 16; ++u) {
                int i = 128 * w + i0 + u;
                #pragma unroll
                for (int r = 0; r < 4; ++r) {
                    float x = xs[r * 768 + i];
                    acc[r][0] += x * wv[u].x; acc[r][1] += x * wv[u].y;
                    acc[r][2] += x * wv[u].z; acc[r][3] += x * wv[u].w;
                }
            }
        }
        // rnn partial: i in [64w, 64w+64)
        const float4* rw4 = (const float4*)(rnn_w + (size_t)m * HIDSZ * HIDSZ);
        for (int i0 = 0; i0 < 64; i0 += 16) {
            float4 wv[16];
            #pragma unroll
            for (int u = 0; u < 16; ++u)
                wv[u] = rw4[(size_t)(64 * w + i0 + u) * 64 + lane];
            #pragma unroll
            for (int u = 0; u < 16; ++u) {
                int i = 64 * w + i0 + u;
                #pragma unroll
                for (int r = 0; r < 4; ++r) {
                    float x = xs[r * 768 + 512 + i];
                    acc[r][0] += x * wv[u].x; acc[r][1] += x * wv[u].y;
                    acc[r][2] += x * wv[u].z; acc[r][3] += x * wv[u].w;
                }
            }
        }
        #pragma unroll
        for (int r = 0; r < 4; ++r)
            *(float4*)&red[w][r][lane * 4] =
                make_float4(acc[r][0], acc[r][1], acc[r][2], acc[r][3]);
        __syncthreads();

        // final: wave w owns row w; sum partials + comm + biases, relu, store
        int ri = g * 4 + w;
        if (ri < R) {
            int b = row_of[s + ri];
            float4 s0 = *(const float4*)&red[0][w][lane * 4];
            float4 s1 = *(const float4*)&red[1][w][lane * 4];
            float4 s2 = *(const float4*)&red[2][w][lane * 4];
            float4 s3 = *(const float4*)&red[3][w][lane * 4];
            float4 cs = make_float4(0.f, 0.f, 0.f, 0.f);
            const float4* ci = (const float4*)(comm_in + (size_t)b * NAGENTS * HIDSZ);
            #pragma unroll
            for (int a = 0; a < NAGENTS; ++a) {
                float4 v = ci[a * 64 + lane];
                cs.x += v.x; cs.y += v.y; cs.z += v.z; cs.w += v.w;
            }
            float4 eb = ((const float4*)enc_b)[lane];
            float4 rb = ((const float4*)(rnn_b + m * HIDSZ))[lane];
            float4 h;
            h.x = fmaxf(s0.x + s1.x + s2.x + s3.x + cs.x + eb.x + rb.x, 0.f);
            h.y = fmaxf(s0.y + s1.y + s2.y + s3.y + cs.y + eb.y + rb.y, 0.f);
            h.z = fmaxf(s0.z + s1.z + s2.z + s3.z + cs.z + eb.z + rb.z, 0.f);
            h.w = fmaxf(s0.w + s1.w + s2.w + s3.w + cs.w + eb.w + rb.w, 0.f);
            ((float4*)(out + OUT_HID))[(size_t)b * 64 + lane] = h;
        }
    }
}

// ---------------- K2: comm_out (y<4) + act softmax / baseline (y==4) ----------
__global__ __launch_bounds__(256) void k_out(
    const float* __restrict__ act_w, const float* __restrict__ act_b,
    const float* __restrict__ base_w, const float* __restrict__ base_b,
    const float* __restrict__ comm_w, const float* __restrict__ comm_b,
    const int* __restrict__ model_start, const int* __restrict__ row_of,
    float* __restrict__ out)
{
    int m = blockIdx.x, y = blockIdx.y;
    int s = model_start[m];
    int R = model_start[m + 1] - s;
    if (R == 0) return;
    int t = threadIdx.x;
    const float* hid = out + OUT_HID;
    __shared__ float hs[16][HIDSZ];   // 16 KB (act uses 16 rows, comm first 8)

    if (y == 4) {
        if (blockIdx.z != 0) return;
        const float* aw = act_w + m * HIDSZ * NACTIONS;
        const float* bw = base_w + m * HIDSZ;
        for (int g = 0; g * 16 < R; ++g) {
            __syncthreads();
            for (int k = t; k < 16 * 64; k += 256) {   // stage 16 rows (float4)
                int rr = k >> 6, l = k & 63;
                int ri = g * 16 + rr;
                float4 v = make_float4(0.f, 0.f, 0.f, 0.f);
                if (ri < R) v = ((const float4*)(hid + (size_t)row_of[s + ri] * HIDSZ))[l];
                ((float4*)hs)[rr * 64 + l] = v;
            }
            __syncthreads();
            {   // action probs: 16 row slots x 16 actions
                int o = t & 15, rs = t >> 4;
                int ri = g * 16 + rs;
                if (ri < R) {
                    int b = row_of[s + ri];
                    float acc = act_b[m * NACTIONS + o];
                    #pragma unroll 8
                    for (int i = 0; i < HIDSZ; ++i)
                        acc += hs[rs][i] * aw[i * NACTIONS + o];
                    float mx = acc;
                    #pragma unroll
                    for (int d = 1; d < 16; d <<= 1) mx = fmaxf(mx, __shfl_xor(mx, d, 64));
                    float ex = __expf(acc - mx);
                    float sm = ex;
                    #pragma unroll
                    for (int d = 1; d < 16; d <<= 1) sm += __shfl_xor(sm, d, 64);
                    out[OUT_ACT + b * NACTIONS + o] = ex / sm;
                }
            }
            {   // baseline: one wave per row
                int lane = t & 63, w = t >> 6;
                for (int rr = w; rr < 16; rr += 4) {
                    int ri = g * 16 + rr;
                    if (ri < R) {
                        int b = row_of[s + ri];
                        float p = 0.f;
                        #pragma unroll
                        for (int i = lane; i < HIDSZ; i += 64)
                            p += hs[rr][i] * bw[i];
                        #pragma unroll
                        for (int d = 1; d < 64; d <<= 1) p += __shfl_xor(p, d, 64);
                        if (lane == 0) out[OUT_BASE + b] = p + base_b[m];
                    }
                }
            }
        }
        return;
    }

    // ---- comm_out: col-quarter y (512 cols), 2 cols/thread (float2),
    //      8-row groups (z), explicit 16-deep load pipeline ----
    int cp = y * 256 + t;                         // float2 column-pair index
    const float2* cw2 = (const float2*)(comm_w + (size_t)m * HIDSZ * COMMSZ);
    float2 cb = ((const float2*)(comm_b + (size_t)m * COMMSZ))[cp];

    for (int g = blockIdx.z; g * 8 < R; g += gridDim.z) {
        __syncthreads();
        for (int k = t; k < 8 * 64; k += 256) {   // stage 8 rows (float4)
            int rr = k >> 6, l = k & 63;
            int ri = g * 8 + rr;
            float4 v = make_float4(0.f, 0.f, 0.f, 0.f);
            if (ri < R) v = ((const float4*)(hid + (size_t)row_of[s + ri] * HIDSZ))[l];
            ((float4*)hs)[rr * 64 + l] = v;
        }
        __syncthreads();

        float acc[8][2];
        #pragma unroll
        for (int r = 0; r < 8; ++r) { acc[r][0] = 0.f; acc[r][1] = 0.f; }

        for (int i0 = 0; i0 < HIDSZ; i0 += 16) {
            float2 wv[16];
            #pragma unroll
            for (int u = 0; u < 16; ++u)
                wv[u] = cw2[(size_t)(i0 + u) * 1024 + cp];
            #pragma unroll
            for (int u = 0; u < 16; ++u) {
                #pragma unroll
                for (int r = 0; r < 8; ++r) {
                    float h = hs[r][i0 + u];
                    acc[r][0] += h * wv[u].x;
                    acc[r][1] += h * wv[u].y;
                }
            }
        }
        #pragma unroll
        for (int r = 0; r < 8; ++r) {
            int ri = g * 8 + r;
            if (ri < R) {
                int b = row_of[s + ri];
                float2 o2;
                o2.x = acc[r][0] + cb.x;
                o2.y = acc[r][1] + cb.y;
                ((float2*)(out + OUT_COMM))[(size_t)b * 1024 + cp] = o2;
            }
        }
    }
}

extern "C" void kernel_launch(void* const* d_in, const int* in_sizes, int n_in,
                              void* d_out, int out_size, void* d_ws, size_t ws_size,
                              hipStream_t stream) {
    const float* inp      = (const float*)d_in[0];
    const float* prev_hid = (const float*)d_in[1];
    const float* comm_in  = (const float*)d_in[2];
    const int*   ids      = (const int*)d_in[3];
    const float* enc_w    = (const float*)d_in[4];
    const float* enc_b    = (const float*)d_in[5];
    const float* rnn_w    = (const float*)d_in[6];
    const float* rnn_b    = (const float*)d_in[7];
    const float* act_w    = (const float*)d_in[8];
    const float* act_b    = (const float*)d_in[9];
    const float* base_w   = (const float*)d_in[10];
    const float* base_b   = (const float*)d_in[11];
    const float* comm_w   = (const float*)d_in[12];
    const float* comm_b   = (const float*)d_in[13];
    float* out = (float*)d_out;

    int* model_start = (int*)d_ws;            // 65 ints
    int* row_of      = model_start + 72;      // 256 ints

    hipLaunchKernelGGL(k_sort, dim3(1), dim3(256), 0, stream,
                       ids, model_start, row_of);
    hipLaunchKernelGGL(k_hid, dim3(64, 2), dim3(256), 0, stream,
                       inp, prev_hid, comm_in, enc_w, enc_b, rnn_w, rnn_b,
                       model_start, row_of, out);
    hipLaunchKernelGGL(k_out, dim3(64, 5, 2), dim3(256), 0, stream,
                       act_w, act_b, base_w, base_b, comm_w, comm_b,
                       model_start, row_of, out);
}

// Round 7
// 249.477 us; speedup vs baseline: 1.4624x; 1.1230x over previous
//
#include <hip/hip_runtime.h>

#define HIDSZ 256
#define NAGENTS 8
#define NMODELS 64
#define NACTIONS 16
#define BN 256
#define IN_DIM 512
#define XDIM 768          // inp(512) + prev_hid(256)
#define COMMSZ 2048

// output flat offsets (f32 elements), return order: action, baseline, hid, comm
#define OUT_ACT 0
#define OUT_BASE (BN * NACTIONS)                    // 4096
#define OUT_HID (OUT_BASE + BN)                     // 4352
#define OUT_COMM (OUT_HID + BN * HIDSZ)             // 69888

// In-block row grouping: list of rows b with ids[b]==m (order irrelevant).
__device__ __forceinline__ int block_rows(const int* __restrict__ ids, int m,
                                          int* rows, int* cnt, int t) {
    if (t == 0) *cnt = 0;
    __syncthreads();
    int id = ids[t];                  // blockDim.x == BN == 256
    if (id == m) { int p = atomicAdd(cnt, 1); rows[p] = t; }
    __syncthreads();
    return *cnt;
}

// ---------------- K1: hid = relu(enc(inp) + rnn(prev_hid) + comm + biases) ----
// Block = (model m, col-half ch). Thread owns one float2 col-pair; the 4 waves
// are 4 reduction slices of the 768-dim (wave==slice -> xs reads broadcast).
// Explicit 16-deep float2 weight pipeline; LDS cross-slice reduction.
__global__ __launch_bounds__(256) void k_hid(
    const float* __restrict__ inp, const float* __restrict__ prev_hid,
    const float* __restrict__ comm_in,
    const float* __restrict__ enc_w, const float* __restrict__ enc_b,
    const float* __restrict__ rnn_w, const float* __restrict__ rnn_b,
    const int* __restrict__ ids, float* __restrict__ out)
{
    int m = blockIdx.x, ch = blockIdx.y;      // ch: which 128-col half
    __shared__ int rows[BN];
    __shared__ int cnt;
    int t = threadIdx.x;
    int R = block_rows(ids, m, rows, &cnt, t);
    if (R == 0) return;

    __shared__ float xs[8][XDIM];             // 24 KB: 8 staged x-rows
    __shared__ float red[4][8][128];          // 16 KB: per-slice partials

    int cp = t & 63;                          // float2 index within the half
    int sl = t >> 6;                          // reduction slice == wave
    int cbase = ch * 128;
    const float2* ew2 = (const float2*)enc_w;                              // [512][128]
    const float2* rw2 = (const float2*)(rnn_w + (size_t)m * HIDSZ * HIDSZ); // [256][128]

    for (int g = 0; g * 8 < R; ++g) {
        __syncthreads();
        // stage 8 rows of x = [inp | prev_hid] as float4 (1536 float4)
        for (int j = t; j < 8 * 192; j += 256) {
            int r = j / 192, q = j % 192;
            int ri = g * 8 + r;
            float4 v = make_float4(0.f, 0.f, 0.f, 0.f);
            if (ri < R) {
                int b = rows[ri];
                v = (q < 128) ? ((const float4*)(inp + (size_t)b * IN_DIM))[q]
                              : ((const float4*)(prev_hid + (size_t)b * HIDSZ))[q - 128];
            }
            ((float4*)xs)[j] = v;
        }
        __syncthreads();

        float a0[8], a1[8];
        #pragma unroll
        for (int r = 0; r < 8; ++r) { a0[r] = 0.f; a1[r] = 0.f; }

        int ibase = sl * 192;                 // this wave's i-range
        for (int i0 = 0; i0 < 192; i0 += 16) {
            float2 wv[16];
            #pragma unroll
            for (int u = 0; u < 16; ++u) {
                int i = ibase + i0 + u;
                wv[u] = (i < IN_DIM) ? ew2[(size_t)i * 128 + ch * 64 + cp]
                                     : rw2[(size_t)(i - IN_DIM) * 128 + ch * 64 + cp];
            }
            #pragma unroll
            for (int u = 0; u < 16; ++u) {
                int i = ibase + i0 + u;
                #pragma unroll
                for (int r = 0; r < 8; ++r) {
                    float x = xs[r][i];       // wave-uniform broadcast
                    a0[r] += x * wv[u].x;
                    a1[r] += x * wv[u].y;
                }
            }
        }
        #pragma unroll
        for (int r = 0; r < 8; ++r)
            *(float2*)&red[sl][r][cp * 2] = make_float2(a0[r], a1[r]);
        __syncthreads();

        // epilogue: 8 rows x 64 col-pairs = 512 items, 2 per thread
        for (int j = t; j < 512; j += 256) {
            int r = j >> 6, q = j & 63;
            int ri = g * 8 + r;
            if (ri < R) {
                int b = rows[ri];
                float2 s = make_float2(0.f, 0.f);
                #pragma unroll
                for (int s4 = 0; s4 < 4; ++s4) {
                    float2 p = *(const float2*)&red[s4][r][q * 2];
                    s.x += p.x; s.y += p.y;
                }
                int c = cbase + q * 2;
                const float2* ci = (const float2*)(comm_in + (size_t)b * NAGENTS * HIDSZ);
                float2 cs = make_float2(0.f, 0.f);
                #pragma unroll
                for (int a = 0; a < NAGENTS; ++a) {
                    float2 v = ci[a * (HIDSZ / 2) + (c >> 1)];
                    cs.x += v.x; cs.y += v.y;
                }
                float2 eb = *(const float2*)(enc_b + c);
                float2 rb = *(const float2*)(rnn_b + m * HIDSZ + c);
                float2 h;
                h.x = fmaxf(s.x + cs.x + eb.x + rb.x, 0.f);
                h.y = fmaxf(s.y + cs.y + eb.y + rb.y, 0.f);
                *(float2*)(out + OUT_HID + (size_t)b * HIDSZ + c) = h;
            }
        }
    }
}

// ---------------- K2: comm_out (y<4) + act softmax / baseline (y==4) ----------
__global__ __launch_bounds__(256) void k_out(
    const float* __restrict__ act_w, const float* __restrict__ act_b,
    const float* __restrict__ base_w, const float* __restrict__ base_b,
    const float* __restrict__ comm_w, const float* __restrict__ comm_b,
    const int* __restrict__ ids, float* __restrict__ out)
{
    int m = blockIdx.x, y = blockIdx.y;
    __shared__ int rows[BN];
    __shared__ int cnt;
    int t = threadIdx.x;
    int R = block_rows(ids, m, rows, &cnt, t);
    if (R == 0) return;
    const float* hid = out + OUT_HID;
    __shared__ float hs[16][HIDSZ];   // 16 KB (act path uses 16 rows, comm 8)

    if (y == 4) {
        if (blockIdx.z != 0) return;
        const float* aw = act_w + m * HIDSZ * NACTIONS;
        const float* bw = base_w + m * HIDSZ;
        for (int g = 0; g * 16 < R; ++g) {
            __syncthreads();
            for (int k = t; k < 16 * 64; k += 256) {   // stage 16 rows (float4)
                int rr = k >> 6, l = k & 63;
                int ri = g * 16 + rr;
                float4 v = make_float4(0.f, 0.f, 0.f, 0.f);
                if (ri < R) v = ((const float4*)(hid + (size_t)rows[ri] * HIDSZ))[l];
                ((float4*)hs)[rr * 64 + l] = v;
            }
            __syncthreads();
            {   // action probs: 16 row slots x 16 actions
                int o = t & 15, rs = t >> 4;
                int ri = g * 16 + rs;
                if (ri < R) {
                    int b = rows[ri];
                    float acc = act_b[m * NACTIONS + o];
                    #pragma unroll 8
                    for (int i = 0; i < HIDSZ; ++i)
                        acc += hs[rs][i] * aw[i * NACTIONS + o];
                    float mx = acc;
                    #pragma unroll
                    for (int d = 1; d < 16; d <<= 1) mx = fmaxf(mx, __shfl_xor(mx, d, 64));
                    float ex = __expf(acc - mx);
                    float sm = ex;
                    #pragma unroll
                    for (int d = 1; d < 16; d <<= 1) sm += __shfl_xor(sm, d, 64);
                    out[OUT_ACT + b * NACTIONS + o] = ex / sm;
                }
            }
            {   // baseline: one wave per row
                int lane = t & 63, w = t >> 6;
                for (int rr = w; rr < 16; rr += 4) {
                    int ri = g * 16 + rr;
                    if (ri < R) {
                        int b = rows[ri];
                        float p = 0.f;
                        #pragma unroll
                        for (int i = lane; i < HIDSZ; i += 64)
                            p += hs[rr][i] * bw[i];
                        #pragma unroll
                        for (int d = 1; d < 64; d <<= 1) p += __shfl_xor(p, d, 64);
                        if (lane == 0) out[OUT_BASE + b] = p + base_b[m];
                    }
                }
            }
        }
        return;
    }

    // ---- comm_out: col-quarter y (512 cols), 2 cols/thread (float2),
    //      8-row groups (z-strided), explicit 16-deep load pipeline ----
    int cp = y * 256 + t;                         // float2 column-pair index
    const float2* cw2 = (const float2*)(comm_w + (size_t)m * HIDSZ * COMMSZ);
    float2 cb = ((const float2*)(comm_b + (size_t)m * COMMSZ))[cp];

    for (int g = blockIdx.z; g * 8 < R; g += gridDim.z) {
        __syncthreads();
        for (int k = t; k < 8 * 64; k += 256) {   // stage 8 rows (float4)
            int rr = k >> 6, l = k & 63;
            int ri = g * 8 + rr;
            float4 v = make_float4(0.f, 0.f, 0.f, 0.f);
            if (ri < R) v = ((const float4*)(hid + (size_t)rows[ri] * HIDSZ))[l];
            ((float4*)hs)[rr * 64 + l] = v;
        }
        __syncthreads();

        float acc[8][2];
        #pragma unroll
        for (int r = 0; r < 8; ++r) { acc[r][0] = 0.f; acc[r][1] = 0.f; }

        for (int i0 = 0; i0 < HIDSZ; i0 += 16) {
            float2 wv[16];
            #pragma unroll
            for (int u = 0; u < 16; ++u)
                wv[u] = cw2[(size_t)(i0 + u) * 1024 + cp];
            #pragma unroll
            for (int u = 0; u < 16; ++u) {
                #pragma unroll
                for (int r = 0; r < 8; ++r) {
                    float h = hs[r][i0 + u];
                    acc[r][0] += h * wv[u].x;
                    acc[r][1] += h * wv[u].y;
                }
            }
        }
        #pragma unroll
        for (int r = 0; r < 8; ++r) {
            int ri = g * 8 + r;
            if (ri < R) {
                int b = rows[ri];
                float2 o2;
                o2.x = acc[r][0] + cb.x;
                o2.y = acc[r][1] + cb.y;
                ((float2*)(out + OUT_COMM))[(size_t)b * 1024 + cp] = o2;
            }
        }
    }
}

extern "C" void kernel_launch(void* const* d_in, const int* in_sizes, int n_in,
                              void* d_out, int out_size, void* d_ws, size_t ws_size,
                              hipStream_t stream) {
    const float* inp      = (const float*)d_in[0];
    const float* prev_hid = (const float*)d_in[1];
    const float* comm_in  = (const float*)d_in[2];
    const int*   ids      = (const int*)d_in[3];
    const float* enc_w    = (const float*)d_in[4];
    const float* enc_b    = (const float*)d_in[5];
    const float* rnn_w    = (const float*)d_in[6];
    const float* rnn_b    = (const float*)d_in[7];
    const float* act_w    = (const float*)d_in[8];
    const float* act_b    = (const float*)d_in[9];
    const float* base_w   = (const float*)d_in[10];
    const float* base_b   = (const float*)d_in[11];
    const float* comm_w   = (const float*)d_in[12];
    const float* comm_b   = (const float*)d_in[13];
    float* out = (float*)d_out;

    hipLaunchKernelGGL(k_hid, dim3(64, 2), dim3(256), 0, stream,
                       inp, prev_hid, comm_in, enc_w, enc_b, rnn_w, rnn_b,
                       ids, out);
    hipLaunchKernelGGL(k_out, dim3(64, 5, 2), dim3(256), 0, stream,
                       act_w, act_b, base_w, base_b, comm_w, comm_b,
                       ids, out);
}